// Round 4
// baseline (273.731 us; speedup 1.0000x reference)
//
#include <hip/hip_runtime.h>
#include <math.h>

// DVGO volume-rendering forward, round 4.
// vs round 3:
//  - alpha = 1 - (1+e^x)^-0.5  (exact): one v_exp + one v_rsq replaces
//    softplus/log1p/exp chain. sigmoid via v_rcp+v_exp. Setup divs -> v_rcp.
//  - wave-uniform dead-tail: rays exit the bbox after ~40% of the 558
//    samples; once ballot(any-corner-valid)==0 the remaining chunks store
//    constants (ainv=carry, w=0, rgb=sigma(0) consts) and skip all math.
//    Exit is monotone in t (convex box, origin inside), so this is safe.
//  - grid split into two planar 8 B/voxel arrays: arrA=dens+off(3) bf16,
//    arrB=emo(3) bf16. Off-rays touch only arrA; 8 records per 64 B line.
//  - bf_hi drops the AND mask (low-bit garbage <= 2^-9 relative).

namespace {
constexpr int   kR   = 8192;
constexpr int   kS   = 558;
constexpr int   kG   = 160;
constexpr int   kG2  = kG * kG;
constexpr int   kG3  = kG * kG * kG;
constexpr float kNear = 0.05f;
constexpr float kFar  = 6.0f;
constexpr float kStepWorld = 0.5f * (2.0f / 160.0f);  // STEPSIZE * VOXEL_SIZE
constexpr float kActShift = -13.815509557963774f;     // log(1/(1-1e-6)-1)
constexpr float kLog2e = 1.4426950408889634f;
}

__device__ __forceinline__ float fexp(float x) {   // e^x
  return __builtin_amdgcn_exp2f(x * kLog2e);
}
__device__ __forceinline__ float sigmoidf_(float x) {
  return __builtin_amdgcn_rcpf(1.0f + fexp(-x));
}
__device__ __forceinline__ float bf_lo(unsigned int u) {
  union { unsigned int i; float f; } x; x.i = u << 16; return x.f;
}
__device__ __forceinline__ float bf_hi(unsigned int u) {
  union { unsigned int i; float f; } x; x.i = u; return x.f;  // low bits: noise <= 2^-9 rel
}
__device__ __forceinline__ unsigned int f2bf(float f) {
  union { float f; unsigned int i; } x; x.f = f;
  unsigned int lsb = (x.i >> 16) & 1u;
  return (x.i + 0x7fffu + lsb) >> 16;   // RNE bf16, as uint
}

// ---- repack: planar 7-channel f32 -> arrA (dens+off, 8 B/vox), arrB (emo) ----
__global__ __launch_bounds__(256) void repack_grids(
    const float4* __restrict__ dens4,
    const float4* __restrict__ off4,
    const float4* __restrict__ emo4,
    uint2* __restrict__ arrA,
    uint2* __restrict__ arrB)
{
  const int v4 = blockIdx.x * blockDim.x + threadIdx.x;
  constexpr int kQ = kG3 / 4;  // 1,024,000
  if (v4 >= kQ) return;
  const float4 d  = dens4[v4];
  const float4 f0 = off4[v4];
  const float4 f1 = off4[v4 + kQ];
  const float4 f2 = off4[v4 + 2 * kQ];
  const float4 e0 = emo4[v4];
  const float4 e1 = emo4[v4 + kQ];
  const float4 e2 = emo4[v4 + 2 * kQ];
  const float dv[4]  = {d.x, d.y, d.z, d.w};
  const float f0v[4] = {f0.x, f0.y, f0.z, f0.w};
  const float f1v[4] = {f1.x, f1.y, f1.z, f1.w};
  const float f2v[4] = {f2.x, f2.y, f2.z, f2.w};
  const float e0v[4] = {e0.x, e0.y, e0.z, e0.w};
  const float e1v[4] = {e1.x, e1.y, e1.z, e1.w};
  const float e2v[4] = {e2.x, e2.y, e2.z, e2.w};
  #pragma unroll
  for (int j = 0; j < 4; ++j) {
    uint2 a, b;
    a.x = f2bf(dv[j])  | (f2bf(f0v[j]) << 16);
    a.y = f2bf(f1v[j]) | (f2bf(f2v[j]) << 16);
    b.x = f2bf(e0v[j]) | (f2bf(e1v[j]) << 16);
    b.y = f2bf(e2v[j]);
    arrA[4 * v4 + j] = a;
    arrB[4 * v4 + j] = b;
  }
}

// ---- main: one 64-lane wave per ray ----
__global__ __launch_bounds__(256) void dvgo_fwd(
    const float* __restrict__ rays_o,
    const float* __restrict__ rays_d,
    const float* __restrict__ jitter,
    const int*   __restrict__ em_modes,
    const uint2* __restrict__ arrA,
    const uint2* __restrict__ arrB,
    float* __restrict__ out)
{
  const int tid  = blockIdx.x * blockDim.x + threadIdx.x;
  const int ray  = tid >> 6;
  const int lane = tid & 63;
  if (ray >= kR) return;

  const float ox = rays_o[ray * 3 + 0];
  const float oy = rays_o[ray * 3 + 1];
  const float oz = rays_o[ray * 3 + 2];
  const float dx = rays_d[ray * 3 + 0];
  const float dy = rays_d[ray * 3 + 1];
  const float dz = rays_d[ray * 3 + 2];
  const float jit = jitter[ray];
  const bool  on  = (em_modes[ray] == 1);

  const float vx = (dx == 0.0f) ? 1e-6f : dx;
  const float vy = (dy == 0.0f) ? 1e-6f : dy;
  const float vz = (dz == 0.0f) ? 1e-6f : dz;
  const float ivx = __builtin_amdgcn_rcpf(vx);
  const float ivy = __builtin_amdgcn_rcpf(vy);
  const float ivz = __builtin_amdgcn_rcpf(vz);
  const float rax = ( 1.0f - ox) * ivx, rbx = (-1.0f - ox) * ivx;
  const float ray_a = ( 1.0f - oy) * ivy, rby = (-1.0f - oy) * ivy;
  const float raz = ( 1.0f - oz) * ivz, rbz = (-1.0f - oz) * ivz;
  float tmin = fmaxf(fmaxf(fminf(rax, rbx), fminf(ray_a, rby)), fminf(raz, rbz));
  float tmax = fminf(fminf(fmaxf(rax, rbx), fmaxf(ray_a, rby)), fmaxf(raz, rbz));
  tmin = fminf(fmaxf(tmin, kNear), kFar);
  tmax = fminf(fmaxf(tmax, kNear), kFar);
  const bool  ray_out = (tmax <= tmin);
  const float stepc = kStepWorld *
      __builtin_amdgcn_rsqf(dx * dx + dy * dy + dz * dz);

  float* out_ainv = out;                           // [R, S+1]
  float* out_w    = out + (size_t)kR * (kS + 1);   // [R, S]
  float* out_last = out_w + (size_t)kR * kS;       // [R, 1]
  float* out_rgb  = out_last + kR;                 // [R, S, 3]
  float* out_rm   = out_rgb + (size_t)kR * kS * 3; // [R, 3]

  if (lane == 0) out_ainv[(size_t)ray * (kS + 1)] = 1.0f;

  const float c_base = on ? 1.0f : 0.5f;  // sigma(0) (+sigma(0) if on)

  float carry = 1.0f;
  float accr = 0.0f, accg = 0.0f, accb = 0.0f;
  bool dead = false;

  #pragma unroll 1
  for (int chunk = 0; chunk < (kS + 63) / 64; ++chunk) {
    const int  s      = chunk * 64 + lane;
    const bool active = (s < kS);

    if (!dead) {
      const float t  = tmin + stepc * ((float)s + jit);
      const float px = fmaf(dx, t, ox);
      const float py = fmaf(dy, t, oy);
      const float pz = fmaf(dz, t, oz);
      const bool inb = (px >= -1.0f) & (px <= 1.0f) &
                       (py >= -1.0f) & (py <= 1.0f) &
                       (pz >= -1.0f) & (pz <= 1.0f);
      const bool masked = ray_out || !inb;

      const float fx = (px + 1.0f) * 0.5f * (float)(kG - 1);
      const float fy = (py + 1.0f) * 0.5f * (float)(kG - 1);
      const float fz = (pz + 1.0f) * 0.5f * (float)(kG - 1);
      const int ix = (int)floorf(fx);
      const int iy = (int)floorf(fy);
      const int iz = (int)floorf(fz);

      // any corner of (ix..ix+1, ...) in-grid?
      const bool reach = active &&
          (ix >= -1) && (ix <= kG - 1) &&
          (iy >= -1) && (iy <= kG - 1) &&
          (iz >= -1) && (iz <= kG - 1);
      if (__ballot(reach) == 0ull) {
        dead = true;  // monotone: no later sample re-enters reach
      } else {
        const float wx = fx - (float)ix;
        const float wy = fy - (float)iy;
        const float wz = fz - (float)iz;
        const float x0 = 1.0f - wx, y0 = 1.0f - wy, z0 = 1.0f - wz;
        const float wxy00 = x0 * y0, wxy01 = x0 * wy;
        const float wxy10 = wx * y0, wxy11 = wx * wy;
        float w8[8];
        w8[0] = wxy00 * z0; w8[1] = wxy00 * wz;
        w8[2] = wxy01 * z0; w8[3] = wxy01 * wz;
        w8[4] = wxy10 * z0; w8[5] = wxy10 * wz;
        w8[6] = wxy11 * z0; w8[7] = wxy11 * wz;

        float dsum = 0.0f;
        float o0 = 0.0f, o1 = 0.0f, o2 = 0.0f;
        float e0 = 0.0f, e1 = 0.0f, e2 = 0.0f;

        const bool interior = active &&
            (ix >= 0) && (ix < kG - 1) &&
            (iy >= 0) && (iy < kG - 1) &&
            (iz >= 0) && (iz < kG - 1);

        if (interior) {
          const int base = (ix * kG + iy) * kG + iz;
          #pragma unroll
          for (int c = 0; c < 8; ++c) {
            const int gi = base + ((c >> 2) & 1) * kG2 + ((c >> 1) & 1) * kG + (c & 1);
            const float w = w8[c];
            const uint2 qa = arrA[gi];
            dsum = fmaf(w, bf_lo(qa.x), dsum);
            o0   = fmaf(w, bf_hi(qa.x), o0);
            o1   = fmaf(w, bf_lo(qa.y), o1);
            o2   = fmaf(w, bf_hi(qa.y), o2);
            if (on) {
              const uint2 qb = arrB[gi];
              e0 = fmaf(w, bf_lo(qb.x), e0);
              e1 = fmaf(w, bf_hi(qb.x), e1);
              e2 = fmaf(w, bf_lo(qb.y), e2);
            }
          }
        } else if (reach) {
          #pragma unroll
          for (int c = 0; c < 8; ++c) {
            const int cx = ix + ((c >> 2) & 1);
            const int cy = iy + ((c >> 1) & 1);
            const int cz = iz + (c & 1);
            const bool valid = ((unsigned)cx < (unsigned)kG) &
                               ((unsigned)cy < (unsigned)kG) &
                               ((unsigned)cz < (unsigned)kG);
            const float wv = valid ? w8[c] : 0.0f;
            const int gx = min(max(cx, 0), kG - 1);
            const int gy = min(max(cy, 0), kG - 1);
            const int gz = min(max(cz, 0), kG - 1);
            const int gi = (gx * kG + gy) * kG + gz;
            const uint2 qa = arrA[gi];
            dsum = fmaf(wv, bf_lo(qa.x), dsum);
            o0   = fmaf(wv, bf_hi(qa.x), o0);
            o1   = fmaf(wv, bf_lo(qa.y), o1);
            o2   = fmaf(wv, bf_hi(qa.y), o2);
            if (on) {
              const uint2 qb = arrB[gi];
              e0 = fmaf(wv, bf_lo(qb.x), e0);
              e1 = fmaf(wv, bf_hi(qb.x), e1);
              e2 = fmaf(wv, bf_lo(qb.y), e2);
            }
          }
        }

        // alpha = 1-(1+e^x)^-0.5 exactly equals 1-exp(-softplus(x)*0.5)
        float p = 1.0f;
        if (active && !masked) {
          const float ex = fexp(dsum + kActShift);
          p = fmaxf(__builtin_amdgcn_rsqf(1.0f + ex), 1e-10f);
        }
        const float alpha = 1.0f - p;

        // wave-wide inclusive prefix product
        float incl = p;
        #pragma unroll
        for (int o = 1; o < 64; o <<= 1) {
          const float n = __shfl_up(incl, o, 64);
          if (lane >= o) incl *= n;
        }
        float excl = __shfl_up(incl, 1, 64);
        if (lane == 0) excl = 1.0f;
        const float ainv_prev = carry * excl;
        const float ainv_next = carry * incl;
        const float wgt = alpha * ainv_prev;
        carry *= __shfl(incl, 63, 64);

        float rr = sigmoidf_(o0);
        float gg = sigmoidf_(o1);
        float bb = sigmoidf_(o2);
        if (on) {
          rr += sigmoidf_(e0);
          gg += sigmoidf_(e1);
          bb += sigmoidf_(e2);
        }

        if (active) {
          out_ainv[(size_t)ray * (kS + 1) + s + 1] = ainv_next;
          out_w[(size_t)ray * kS + s] = wgt;
          const size_t rb = ((size_t)ray * kS + s) * 3;
          out_rgb[rb + 0] = rr;
          out_rgb[rb + 1] = gg;
          out_rgb[rb + 2] = bb;
          accr = fmaf(wgt, rr, accr);
          accg = fmaf(wgt, gg, accg);
          accb = fmaf(wgt, bb, accb);
        }
        continue;  // live chunk handled
      }
    }

    // dead tail: alpha=0, p=1, sampler output 0 -> rgb consts
    if (active) {
      out_ainv[(size_t)ray * (kS + 1) + s + 1] = carry;
      out_w[(size_t)ray * kS + s] = 0.0f;
      const size_t rb = ((size_t)ray * kS + s) * 3;
      out_rgb[rb + 0] = c_base;
      out_rgb[rb + 1] = c_base;
      out_rgb[rb + 2] = c_base;
    }
  }

  #pragma unroll
  for (int o = 32; o > 0; o >>= 1) {
    accr += __shfl_xor(accr, o, 64);
    accg += __shfl_xor(accg, o, 64);
    accb += __shfl_xor(accb, o, 64);
  }
  if (lane == 0) {
    out_last[ray] = carry;
    out_rm[(size_t)ray * 3 + 0] = accr;
    out_rm[(size_t)ray * 3 + 1] = accg;
    out_rm[(size_t)ray * 3 + 2] = accb;
  }
}

extern "C" void kernel_launch(void* const* d_in, const int* in_sizes, int n_in,
                              void* d_out, int out_size, void* d_ws, size_t ws_size,
                              hipStream_t stream) {
  const float* rays_o  = (const float*)d_in[0];
  const float* rays_d  = (const float*)d_in[1];
  const float* jitter  = (const float*)d_in[2];
  const int*   em      = (const int*)d_in[3];
  const float* density = (const float*)d_in[4];
  const float* off_c   = (const float*)d_in[5];
  const float* emo_c   = (const float*)d_in[6];
  float* out = (float*)d_out;

  uint2* arrA = (uint2*)d_ws;                 // 32.8 MB
  uint2* arrB = arrA + kG3;                   // 32.8 MB
  (void)ws_size;

  constexpr int kQ = kG3 / 4;
  hipLaunchKernelGGL(repack_grids, dim3((kQ + 255) / 256), dim3(256), 0,
                     stream, (const float4*)density, (const float4*)off_c,
                     (const float4*)emo_c, arrA, arrB);

  const int threads = 256;
  const int blocks  = (kR * 64) / threads;  // 2048
  hipLaunchKernelGGL(dvgo_fwd, dim3(blocks), dim3(threads), 0, stream,
                     rays_o, rays_d, jitter, em, arrA, arrB, out);
}

// Round 5
// 249.427 us; speedup vs baseline: 1.0974x; 1.0974x over previous
//
#include <hip/hip_runtime.h>
#include <math.h>

// DVGO volume-rendering forward, round 5.
// = round 3's 16 B/voxel interleaved grid layout (one corner -> ONE cache
//   line; on-rays: single dwordx4, off-rays: first 8 B of the same slot)
// + round 4's wave-uniform dead-tail skip and exp2/rsq/rcp transcendentals.
// Round-4 post-mortem: planar A/B split doubled on-ray line traffic
// (FETCH 105->169 MB) and regressed; dead-tail skip cut VALUBusy 48->16%.
// This round keeps the VALU win and restores the 105 MB fetch.

namespace {
constexpr int   kR   = 8192;
constexpr int   kS   = 558;
constexpr int   kG   = 160;
constexpr int   kG2  = kG * kG;
constexpr int   kG3  = kG * kG * kG;
constexpr float kNear = 0.05f;
constexpr float kFar  = 6.0f;
constexpr float kStepWorld = 0.5f * (2.0f / 160.0f);  // STEPSIZE * VOXEL_SIZE
constexpr float kActShift = -13.815509557963774f;     // log(1/(1-1e-6)-1)
constexpr float kLog2e = 1.4426950408889634f;
}

__device__ __forceinline__ float fexp(float x) {   // e^x
  return __builtin_amdgcn_exp2f(x * kLog2e);
}
__device__ __forceinline__ float sigmoidf_(float x) {
  return __builtin_amdgcn_rcpf(1.0f + fexp(-x));
}
__device__ __forceinline__ float bf_lo(unsigned int u) {
  union { unsigned int i; float f; } x; x.i = u << 16; return x.f;
}
__device__ __forceinline__ float bf_hi(unsigned int u) {
  union { unsigned int i; float f; } x; x.i = u; return x.f;  // low-bit noise <= 2^-9 rel
}
__device__ __forceinline__ unsigned int f2bf(float f) {
  union { float f; unsigned int i; } x; x.f = f;
  unsigned int lsb = (x.i >> 16) & 1u;
  return (x.i + 0x7fffu + lsb) >> 16;   // RNE bf16, as uint
}

// ---- repack: planar 7-channel f32 -> interleaved 8 x bf16 (16 B/voxel) ----
__global__ __launch_bounds__(256) void repack_grids(
    const float4* __restrict__ dens4,
    const float4* __restrict__ off4,
    const float4* __restrict__ emo4,
    uint4* __restrict__ packed)
{
  const int v4 = blockIdx.x * blockDim.x + threadIdx.x;
  constexpr int kQ = kG3 / 4;  // 1,024,000
  if (v4 >= kQ) return;
  const float4 d  = dens4[v4];
  const float4 f0 = off4[v4];
  const float4 f1 = off4[v4 + kQ];
  const float4 f2 = off4[v4 + 2 * kQ];
  const float4 e0 = emo4[v4];
  const float4 e1 = emo4[v4 + kQ];
  const float4 e2 = emo4[v4 + 2 * kQ];
  const float dv[4]  = {d.x, d.y, d.z, d.w};
  const float f0v[4] = {f0.x, f0.y, f0.z, f0.w};
  const float f1v[4] = {f1.x, f1.y, f1.z, f1.w};
  const float f2v[4] = {f2.x, f2.y, f2.z, f2.w};
  const float e0v[4] = {e0.x, e0.y, e0.z, e0.w};
  const float e1v[4] = {e1.x, e1.y, e1.z, e1.w};
  const float e2v[4] = {e2.x, e2.y, e2.z, e2.w};
  #pragma unroll
  for (int j = 0; j < 4; ++j) {
    uint4 q;
    q.x = f2bf(dv[j])  | (f2bf(f0v[j]) << 16);  // dens | off0
    q.y = f2bf(f1v[j]) | (f2bf(f2v[j]) << 16);  // off1 | off2
    q.z = f2bf(e0v[j]) | (f2bf(e1v[j]) << 16);  // emo0 | emo1
    q.w = f2bf(e2v[j]);                         // emo2 | pad
    packed[4 * v4 + j] = q;
  }
}

// ---- main: one 64-lane wave per ray ----
__global__ __launch_bounds__(256) void dvgo_fwd(
    const float* __restrict__ rays_o,
    const float* __restrict__ rays_d,
    const float* __restrict__ jitter,
    const int*   __restrict__ em_modes,
    const uint4* __restrict__ packed4,
    const uint2* __restrict__ packed2,  // same buffer, 2 x uint2 per voxel
    float* __restrict__ out)
{
  const int tid  = blockIdx.x * blockDim.x + threadIdx.x;
  const int ray  = tid >> 6;
  const int lane = tid & 63;
  if (ray >= kR) return;

  const float ox = rays_o[ray * 3 + 0];
  const float oy = rays_o[ray * 3 + 1];
  const float oz = rays_o[ray * 3 + 2];
  const float dx = rays_d[ray * 3 + 0];
  const float dy = rays_d[ray * 3 + 1];
  const float dz = rays_d[ray * 3 + 2];
  const float jit = jitter[ray];
  const bool  on  = (em_modes[ray] == 1);

  const float vx = (dx == 0.0f) ? 1e-6f : dx;
  const float vy = (dy == 0.0f) ? 1e-6f : dy;
  const float vz = (dz == 0.0f) ? 1e-6f : dz;
  const float ivx = __builtin_amdgcn_rcpf(vx);
  const float ivy = __builtin_amdgcn_rcpf(vy);
  const float ivz = __builtin_amdgcn_rcpf(vz);
  const float rax = ( 1.0f - ox) * ivx, rbx = (-1.0f - ox) * ivx;
  const float ray_a = ( 1.0f - oy) * ivy, rby = (-1.0f - oy) * ivy;
  const float raz = ( 1.0f - oz) * ivz, rbz = (-1.0f - oz) * ivz;
  float tmin = fmaxf(fmaxf(fminf(rax, rbx), fminf(ray_a, rby)), fminf(raz, rbz));
  float tmax = fminf(fminf(fmaxf(rax, rbx), fmaxf(ray_a, rby)), fmaxf(raz, rbz));
  tmin = fminf(fmaxf(tmin, kNear), kFar);
  tmax = fminf(fmaxf(tmax, kNear), kFar);
  const bool  ray_out = (tmax <= tmin);
  const float stepc = kStepWorld *
      __builtin_amdgcn_rsqf(dx * dx + dy * dy + dz * dz);

  float* out_ainv = out;                           // [R, S+1]
  float* out_w    = out + (size_t)kR * (kS + 1);   // [R, S]
  float* out_last = out_w + (size_t)kR * kS;       // [R, 1]
  float* out_rgb  = out_last + kR;                 // [R, S, 3]
  float* out_rm   = out_rgb + (size_t)kR * kS * 3; // [R, 3]

  if (lane == 0) out_ainv[(size_t)ray * (kS + 1)] = 1.0f;

  const float c_base = on ? 1.0f : 0.5f;  // sigma(0) (+sigma(0) if on)

  float carry = 1.0f;
  float accr = 0.0f, accg = 0.0f, accb = 0.0f;
  bool dead = false;

  #pragma unroll 1
  for (int chunk = 0; chunk < (kS + 63) / 64; ++chunk) {
    const int  s      = chunk * 64 + lane;
    const bool active = (s < kS);

    if (!dead) {
      const float t  = tmin + stepc * ((float)s + jit);
      const float px = fmaf(dx, t, ox);
      const float py = fmaf(dy, t, oy);
      const float pz = fmaf(dz, t, oz);
      const bool inb = (px >= -1.0f) & (px <= 1.0f) &
                       (py >= -1.0f) & (py <= 1.0f) &
                       (pz >= -1.0f) & (pz <= 1.0f);
      const bool masked = ray_out || !inb;

      const float fx = (px + 1.0f) * 0.5f * (float)(kG - 1);
      const float fy = (py + 1.0f) * 0.5f * (float)(kG - 1);
      const float fz = (pz + 1.0f) * 0.5f * (float)(kG - 1);
      const int ix = (int)floorf(fx);
      const int iy = (int)floorf(fy);
      const int iz = (int)floorf(fz);

      const bool reach = active &&
          (ix >= -1) && (ix <= kG - 1) &&
          (iy >= -1) && (iy <= kG - 1) &&
          (iz >= -1) && (iz <= kG - 1);
      if (__ballot(reach) == 0ull) {
        dead = true;  // monotone: no later sample re-enters reach
      } else {
        const float wx = fx - (float)ix;
        const float wy = fy - (float)iy;
        const float wz = fz - (float)iz;
        const float x0 = 1.0f - wx, y0 = 1.0f - wy, z0 = 1.0f - wz;
        const float wxy00 = x0 * y0, wxy01 = x0 * wy;
        const float wxy10 = wx * y0, wxy11 = wx * wy;
        float w8[8];
        w8[0] = wxy00 * z0; w8[1] = wxy00 * wz;
        w8[2] = wxy01 * z0; w8[3] = wxy01 * wz;
        w8[4] = wxy10 * z0; w8[5] = wxy10 * wz;
        w8[6] = wxy11 * z0; w8[7] = wxy11 * wz;

        float dsum = 0.0f;
        float o0 = 0.0f, o1 = 0.0f, o2 = 0.0f;
        float e0 = 0.0f, e1 = 0.0f, e2 = 0.0f;

        const bool interior = active &&
            (ix >= 0) && (ix < kG - 1) &&
            (iy >= 0) && (iy < kG - 1) &&
            (iz >= 0) && (iz < kG - 1);

        if (interior) {
          const int base = (ix * kG + iy) * kG + iz;
          if (on) {
            #pragma unroll
            for (int c = 0; c < 8; ++c) {
              const int gi = base + ((c >> 2) & 1) * kG2 + ((c >> 1) & 1) * kG + (c & 1);
              const float w = w8[c];
              const uint4 q = packed4[gi];
              dsum = fmaf(w, bf_lo(q.x), dsum);
              o0   = fmaf(w, bf_hi(q.x), o0);
              o1   = fmaf(w, bf_lo(q.y), o1);
              o2   = fmaf(w, bf_hi(q.y), o2);
              e0   = fmaf(w, bf_lo(q.z), e0);
              e1   = fmaf(w, bf_hi(q.z), e1);
              e2   = fmaf(w, bf_lo(q.w), e2);
            }
          } else {
            #pragma unroll
            for (int c = 0; c < 8; ++c) {
              const int gi = base + ((c >> 2) & 1) * kG2 + ((c >> 1) & 1) * kG + (c & 1);
              const float w = w8[c];
              const uint2 qa = packed2[(size_t)gi * 2];
              dsum = fmaf(w, bf_lo(qa.x), dsum);
              o0   = fmaf(w, bf_hi(qa.x), o0);
              o1   = fmaf(w, bf_lo(qa.y), o1);
              o2   = fmaf(w, bf_hi(qa.y), o2);
            }
          }
        } else if (reach) {
          #pragma unroll
          for (int c = 0; c < 8; ++c) {
            const int cx = ix + ((c >> 2) & 1);
            const int cy = iy + ((c >> 1) & 1);
            const int cz = iz + (c & 1);
            const bool valid = ((unsigned)cx < (unsigned)kG) &
                               ((unsigned)cy < (unsigned)kG) &
                               ((unsigned)cz < (unsigned)kG);
            const float wv = valid ? w8[c] : 0.0f;
            const int gx = min(max(cx, 0), kG - 1);
            const int gy = min(max(cy, 0), kG - 1);
            const int gz = min(max(cz, 0), kG - 1);
            const int gi = (gx * kG + gy) * kG + gz;
            const uint2 qa = packed2[(size_t)gi * 2];
            dsum = fmaf(wv, bf_lo(qa.x), dsum);
            o0   = fmaf(wv, bf_hi(qa.x), o0);
            o1   = fmaf(wv, bf_lo(qa.y), o1);
            o2   = fmaf(wv, bf_hi(qa.y), o2);
            if (on) {
              const uint2 qb = packed2[(size_t)gi * 2 + 1];
              e0 = fmaf(wv, bf_lo(qb.x), e0);
              e1 = fmaf(wv, bf_hi(qb.x), e1);
              e2 = fmaf(wv, bf_lo(qb.y), e2);
            }
          }
        }

        // alpha = 1-(1+e^x)^-0.5 == 1-exp(-softplus(x)*0.5) exactly
        float p = 1.0f;
        if (active && !masked) {
          const float ex = fexp(dsum + kActShift);
          p = fmaxf(__builtin_amdgcn_rsqf(1.0f + ex), 1e-10f);
        }
        const float alpha = 1.0f - p;

        float incl = p;
        #pragma unroll
        for (int o = 1; o < 64; o <<= 1) {
          const float n = __shfl_up(incl, o, 64);
          if (lane >= o) incl *= n;
        }
        float excl = __shfl_up(incl, 1, 64);
        if (lane == 0) excl = 1.0f;
        const float ainv_prev = carry * excl;
        const float ainv_next = carry * incl;
        const float wgt = alpha * ainv_prev;
        carry *= __shfl(incl, 63, 64);

        float rr = sigmoidf_(o0);
        float gg = sigmoidf_(o1);
        float bb = sigmoidf_(o2);
        if (on) {
          rr += sigmoidf_(e0);
          gg += sigmoidf_(e1);
          bb += sigmoidf_(e2);
        }

        if (active) {
          out_ainv[(size_t)ray * (kS + 1) + s + 1] = ainv_next;
          out_w[(size_t)ray * kS + s] = wgt;
          const size_t rb = ((size_t)ray * kS + s) * 3;
          out_rgb[rb + 0] = rr;
          out_rgb[rb + 1] = gg;
          out_rgb[rb + 2] = bb;
          accr = fmaf(wgt, rr, accr);
          accg = fmaf(wgt, gg, accg);
          accb = fmaf(wgt, bb, accb);
        }
        continue;  // live chunk handled
      }
    }

    // dead tail: alpha=0, p=1, sampler output 0 -> rgb consts
    if (active) {
      out_ainv[(size_t)ray * (kS + 1) + s + 1] = carry;
      out_w[(size_t)ray * kS + s] = 0.0f;
      const size_t rb = ((size_t)ray * kS + s) * 3;
      out_rgb[rb + 0] = c_base;
      out_rgb[rb + 1] = c_base;
      out_rgb[rb + 2] = c_base;
    }
  }

  #pragma unroll
  for (int o = 32; o > 0; o >>= 1) {
    accr += __shfl_xor(accr, o, 64);
    accg += __shfl_xor(accg, o, 64);
    accb += __shfl_xor(accb, o, 64);
  }
  if (lane == 0) {
    out_last[ray] = carry;
    out_rm[(size_t)ray * 3 + 0] = accr;
    out_rm[(size_t)ray * 3 + 1] = accg;
    out_rm[(size_t)ray * 3 + 2] = accb;
  }
}

extern "C" void kernel_launch(void* const* d_in, const int* in_sizes, int n_in,
                              void* d_out, int out_size, void* d_ws, size_t ws_size,
                              hipStream_t stream) {
  const float* rays_o  = (const float*)d_in[0];
  const float* rays_d  = (const float*)d_in[1];
  const float* jitter  = (const float*)d_in[2];
  const int*   em      = (const int*)d_in[3];
  const float* density = (const float*)d_in[4];
  const float* off_c   = (const float*)d_in[5];
  const float* emo_c   = (const float*)d_in[6];
  float* out = (float*)d_out;

  uint4* packed = (uint4*)d_ws;  // 65.5 MB
  (void)ws_size;

  constexpr int kQ = kG3 / 4;
  hipLaunchKernelGGL(repack_grids, dim3((kQ + 255) / 256), dim3(256), 0,
                     stream, (const float4*)density, (const float4*)off_c,
                     (const float4*)emo_c, packed);

  const int threads = 256;
  const int blocks  = (kR * 64) / threads;  // 2048
  hipLaunchKernelGGL(dvgo_fwd, dim3(blocks), dim3(threads), 0, stream,
                     rays_o, rays_d, jitter, em, packed,
                     (const uint2*)packed, out);
}

// Round 7
// 239.694 us; speedup vs baseline: 1.1420x; 1.0406x over previous
//
#include <hip/hip_runtime.h>
#include <math.h>

// DVGO volume-rendering forward, round 7 (round 6 + compile fix).
// Round-6 compile error: __builtin_nontemporal_store rejects HIP's class-
// type uint4 — use a Clang native vector (ext_vector_type) for the 16 B NT
// store. Everything else per round-6 theory:
//  - repack: one voxel/thread, 7 coalesced scalar NT loads + ONE coalesced
//    16 B/lane NT store (round-5 repack scattered stores across 64 lines).
//  - main kernel: NT stores for the 93 MB write-once outputs -> preserve L2
//    for gather lines.
// Main structure (16 B/voxel interleaved bf16 grid, wave/ray, dead-tail
// skip, exp2/rsq transcendentals) unchanged from round 5.

namespace {
constexpr int   kR   = 8192;
constexpr int   kS   = 558;
constexpr int   kG   = 160;
constexpr int   kG2  = kG * kG;
constexpr int   kG3  = kG * kG * kG;
constexpr float kNear = 0.05f;
constexpr float kFar  = 6.0f;
constexpr float kStepWorld = 0.5f * (2.0f / 160.0f);  // STEPSIZE * VOXEL_SIZE
constexpr float kActShift = -13.815509557963774f;     // log(1/(1-1e-6)-1)
constexpr float kLog2e = 1.4426950408889634f;
}

typedef unsigned int nuint4 __attribute__((ext_vector_type(4)));

__device__ __forceinline__ float fexp(float x) {   // e^x
  return __builtin_amdgcn_exp2f(x * kLog2e);
}
__device__ __forceinline__ float sigmoidf_(float x) {
  return __builtin_amdgcn_rcpf(1.0f + fexp(-x));
}
__device__ __forceinline__ float bf_lo(unsigned int u) {
  union { unsigned int i; float f; } x; x.i = u << 16; return x.f;
}
__device__ __forceinline__ float bf_hi(unsigned int u) {
  union { unsigned int i; float f; } x; x.i = u; return x.f;  // low-bit noise <= 2^-9 rel
}
__device__ __forceinline__ unsigned int f2bf(float f) {
  union { float f; unsigned int i; } x; x.f = f;
  unsigned int lsb = (x.i >> 16) & 1u;
  return (x.i + 0x7fffu + lsb) >> 16;   // RNE bf16, as uint
}

// ---- repack: planar 7-channel f32 -> interleaved 8 x bf16 (16 B/voxel) ----
__global__ __launch_bounds__(256) void repack_grids(
    const float* __restrict__ density,
    const float* __restrict__ off_c,
    const float* __restrict__ emo_c,
    nuint4* __restrict__ packed)
{
  const int v = blockIdx.x * blockDim.x + threadIdx.x;
  if (v >= kG3) return;
  const float d  = __builtin_nontemporal_load(density + v);
  const float f0 = __builtin_nontemporal_load(off_c + v);
  const float f1 = __builtin_nontemporal_load(off_c + v + kG3);
  const float f2 = __builtin_nontemporal_load(off_c + v + 2 * kG3);
  const float e0 = __builtin_nontemporal_load(emo_c + v);
  const float e1 = __builtin_nontemporal_load(emo_c + v + kG3);
  const float e2 = __builtin_nontemporal_load(emo_c + v + 2 * kG3);
  nuint4 q;
  q.x = f2bf(d)  | (f2bf(f0) << 16);  // dens | off0
  q.y = f2bf(f1) | (f2bf(f2) << 16);  // off1 | off2
  q.z = f2bf(e0) | (f2bf(e1) << 16);  // emo0 | emo1
  q.w = f2bf(e2);                     // emo2 | pad
  __builtin_nontemporal_store(q, packed + v);
}

// ---- main: one 64-lane wave per ray ----
__global__ __launch_bounds__(256) void dvgo_fwd(
    const float* __restrict__ rays_o,
    const float* __restrict__ rays_d,
    const float* __restrict__ jitter,
    const int*   __restrict__ em_modes,
    const uint4* __restrict__ packed4,
    const uint2* __restrict__ packed2,  // same buffer, 2 x uint2 per voxel
    float* __restrict__ out)
{
  const int tid  = blockIdx.x * blockDim.x + threadIdx.x;
  const int ray  = tid >> 6;
  const int lane = tid & 63;
  if (ray >= kR) return;

  const float ox = rays_o[ray * 3 + 0];
  const float oy = rays_o[ray * 3 + 1];
  const float oz = rays_o[ray * 3 + 2];
  const float dx = rays_d[ray * 3 + 0];
  const float dy = rays_d[ray * 3 + 1];
  const float dz = rays_d[ray * 3 + 2];
  const float jit = jitter[ray];
  const bool  on  = (em_modes[ray] == 1);

  const float vx = (dx == 0.0f) ? 1e-6f : dx;
  const float vy = (dy == 0.0f) ? 1e-6f : dy;
  const float vz = (dz == 0.0f) ? 1e-6f : dz;
  const float ivx = __builtin_amdgcn_rcpf(vx);
  const float ivy = __builtin_amdgcn_rcpf(vy);
  const float ivz = __builtin_amdgcn_rcpf(vz);
  const float rax = ( 1.0f - ox) * ivx, rbx = (-1.0f - ox) * ivx;
  const float ray_a = ( 1.0f - oy) * ivy, rby = (-1.0f - oy) * ivy;
  const float raz = ( 1.0f - oz) * ivz, rbz = (-1.0f - oz) * ivz;
  float tmin = fmaxf(fmaxf(fminf(rax, rbx), fminf(ray_a, rby)), fminf(raz, rbz));
  float tmax = fminf(fminf(fmaxf(rax, rbx), fmaxf(ray_a, rby)), fmaxf(raz, rbz));
  tmin = fminf(fmaxf(tmin, kNear), kFar);
  tmax = fminf(fmaxf(tmax, kNear), kFar);
  const bool  ray_out = (tmax <= tmin);
  const float stepc = kStepWorld *
      __builtin_amdgcn_rsqf(dx * dx + dy * dy + dz * dz);

  float* out_ainv = out;                           // [R, S+1]
  float* out_w    = out + (size_t)kR * (kS + 1);   // [R, S]
  float* out_last = out_w + (size_t)kR * kS;       // [R, 1]
  float* out_rgb  = out_last + kR;                 // [R, S, 3]
  float* out_rm   = out_rgb + (size_t)kR * kS * 3; // [R, 3]

  if (lane == 0)
    __builtin_nontemporal_store(1.0f, out_ainv + (size_t)ray * (kS + 1));

  const float c_base = on ? 1.0f : 0.5f;  // sigma(0) (+sigma(0) if on)

  float carry = 1.0f;
  float accr = 0.0f, accg = 0.0f, accb = 0.0f;
  bool dead = false;

  #pragma unroll 1
  for (int chunk = 0; chunk < (kS + 63) / 64; ++chunk) {
    const int  s      = chunk * 64 + lane;
    const bool active = (s < kS);

    if (!dead) {
      const float t  = tmin + stepc * ((float)s + jit);
      const float px = fmaf(dx, t, ox);
      const float py = fmaf(dy, t, oy);
      const float pz = fmaf(dz, t, oz);
      const bool inb = (px >= -1.0f) & (px <= 1.0f) &
                       (py >= -1.0f) & (py <= 1.0f) &
                       (pz >= -1.0f) & (pz <= 1.0f);
      const bool masked = ray_out || !inb;

      const float fx = (px + 1.0f) * 0.5f * (float)(kG - 1);
      const float fy = (py + 1.0f) * 0.5f * (float)(kG - 1);
      const float fz = (pz + 1.0f) * 0.5f * (float)(kG - 1);
      const int ix = (int)floorf(fx);
      const int iy = (int)floorf(fy);
      const int iz = (int)floorf(fz);

      const bool reach = active &&
          (ix >= -1) && (ix <= kG - 1) &&
          (iy >= -1) && (iy <= kG - 1) &&
          (iz >= -1) && (iz <= kG - 1);
      if (__ballot(reach) == 0ull) {
        dead = true;  // monotone: no later sample re-enters reach
      } else {
        const float wx = fx - (float)ix;
        const float wy = fy - (float)iy;
        const float wz = fz - (float)iz;
        const float x0 = 1.0f - wx, y0 = 1.0f - wy, z0 = 1.0f - wz;
        const float wxy00 = x0 * y0, wxy01 = x0 * wy;
        const float wxy10 = wx * y0, wxy11 = wx * wy;
        float w8[8];
        w8[0] = wxy00 * z0; w8[1] = wxy00 * wz;
        w8[2] = wxy01 * z0; w8[3] = wxy01 * wz;
        w8[4] = wxy10 * z0; w8[5] = wxy10 * wz;
        w8[6] = wxy11 * z0; w8[7] = wxy11 * wz;

        float dsum = 0.0f;
        float o0 = 0.0f, o1 = 0.0f, o2 = 0.0f;
        float e0 = 0.0f, e1 = 0.0f, e2 = 0.0f;

        const bool interior = active &&
            (ix >= 0) && (ix < kG - 1) &&
            (iy >= 0) && (iy < kG - 1) &&
            (iz >= 0) && (iz < kG - 1);

        if (interior) {
          const int base = (ix * kG + iy) * kG + iz;
          if (on) {
            #pragma unroll
            for (int c = 0; c < 8; ++c) {
              const int gi = base + ((c >> 2) & 1) * kG2 + ((c >> 1) & 1) * kG + (c & 1);
              const float w = w8[c];
              const uint4 q = packed4[gi];
              dsum = fmaf(w, bf_lo(q.x), dsum);
              o0   = fmaf(w, bf_hi(q.x), o0);
              o1   = fmaf(w, bf_lo(q.y), o1);
              o2   = fmaf(w, bf_hi(q.y), o2);
              e0   = fmaf(w, bf_lo(q.z), e0);
              e1   = fmaf(w, bf_hi(q.z), e1);
              e2   = fmaf(w, bf_lo(q.w), e2);
            }
          } else {
            #pragma unroll
            for (int c = 0; c < 8; ++c) {
              const int gi = base + ((c >> 2) & 1) * kG2 + ((c >> 1) & 1) * kG + (c & 1);
              const float w = w8[c];
              const uint2 qa = packed2[(size_t)gi * 2];
              dsum = fmaf(w, bf_lo(qa.x), dsum);
              o0   = fmaf(w, bf_hi(qa.x), o0);
              o1   = fmaf(w, bf_lo(qa.y), o1);
              o2   = fmaf(w, bf_hi(qa.y), o2);
            }
          }
        } else if (reach) {
          #pragma unroll
          for (int c = 0; c < 8; ++c) {
            const int cx = ix + ((c >> 2) & 1);
            const int cy = iy + ((c >> 1) & 1);
            const int cz = iz + (c & 1);
            const bool valid = ((unsigned)cx < (unsigned)kG) &
                               ((unsigned)cy < (unsigned)kG) &
                               ((unsigned)cz < (unsigned)kG);
            const float wv = valid ? w8[c] : 0.0f;
            const int gx = min(max(cx, 0), kG - 1);
            const int gy = min(max(cy, 0), kG - 1);
            const int gz = min(max(cz, 0), kG - 1);
            const int gi = (gx * kG + gy) * kG + gz;
            const uint2 qa = packed2[(size_t)gi * 2];
            dsum = fmaf(wv, bf_lo(qa.x), dsum);
            o0   = fmaf(wv, bf_hi(qa.x), o0);
            o1   = fmaf(wv, bf_lo(qa.y), o1);
            o2   = fmaf(wv, bf_hi(qa.y), o2);
            if (on) {
              const uint2 qb = packed2[(size_t)gi * 2 + 1];
              e0 = fmaf(wv, bf_lo(qb.x), e0);
              e1 = fmaf(wv, bf_hi(qb.x), e1);
              e2 = fmaf(wv, bf_lo(qb.y), e2);
            }
          }
        }

        // alpha = 1-(1+e^x)^-0.5 == 1-exp(-softplus(x)*0.5) exactly
        float p = 1.0f;
        if (active && !masked) {
          const float ex = fexp(dsum + kActShift);
          p = fmaxf(__builtin_amdgcn_rsqf(1.0f + ex), 1e-10f);
        }
        const float alpha = 1.0f - p;

        float incl = p;
        #pragma unroll
        for (int o = 1; o < 64; o <<= 1) {
          const float n = __shfl_up(incl, o, 64);
          if (lane >= o) incl *= n;
        }
        float excl = __shfl_up(incl, 1, 64);
        if (lane == 0) excl = 1.0f;
        const float ainv_prev = carry * excl;
        const float ainv_next = carry * incl;
        const float wgt = alpha * ainv_prev;
        carry *= __shfl(incl, 63, 64);

        float rr = sigmoidf_(o0);
        float gg = sigmoidf_(o1);
        float bb = sigmoidf_(o2);
        if (on) {
          rr += sigmoidf_(e0);
          gg += sigmoidf_(e1);
          bb += sigmoidf_(e2);
        }

        if (active) {
          __builtin_nontemporal_store(ainv_next,
              out_ainv + (size_t)ray * (kS + 1) + s + 1);
          __builtin_nontemporal_store(wgt, out_w + (size_t)ray * kS + s);
          const size_t rb = ((size_t)ray * kS + s) * 3;
          __builtin_nontemporal_store(rr, out_rgb + rb + 0);
          __builtin_nontemporal_store(gg, out_rgb + rb + 1);
          __builtin_nontemporal_store(bb, out_rgb + rb + 2);
          accr = fmaf(wgt, rr, accr);
          accg = fmaf(wgt, gg, accg);
          accb = fmaf(wgt, bb, accb);
        }
        continue;  // live chunk handled
      }
    }

    // dead tail: alpha=0, p=1, sampler output 0 -> rgb consts
    if (active) {
      __builtin_nontemporal_store(carry,
          out_ainv + (size_t)ray * (kS + 1) + s + 1);
      __builtin_nontemporal_store(0.0f, out_w + (size_t)ray * kS + s);
      const size_t rb = ((size_t)ray * kS + s) * 3;
      __builtin_nontemporal_store(c_base, out_rgb + rb + 0);
      __builtin_nontemporal_store(c_base, out_rgb + rb + 1);
      __builtin_nontemporal_store(c_base, out_rgb + rb + 2);
    }
  }

  #pragma unroll
  for (int o = 32; o > 0; o >>= 1) {
    accr += __shfl_xor(accr, o, 64);
    accg += __shfl_xor(accg, o, 64);
    accb += __shfl_xor(accb, o, 64);
  }
  if (lane == 0) {
    out_last[ray] = carry;
    out_rm[(size_t)ray * 3 + 0] = accr;
    out_rm[(size_t)ray * 3 + 1] = accg;
    out_rm[(size_t)ray * 3 + 2] = accb;
  }
}

extern "C" void kernel_launch(void* const* d_in, const int* in_sizes, int n_in,
                              void* d_out, int out_size, void* d_ws, size_t ws_size,
                              hipStream_t stream) {
  const float* rays_o  = (const float*)d_in[0];
  const float* rays_d  = (const float*)d_in[1];
  const float* jitter  = (const float*)d_in[2];
  const int*   em      = (const int*)d_in[3];
  const float* density = (const float*)d_in[4];
  const float* off_c   = (const float*)d_in[5];
  const float* emo_c   = (const float*)d_in[6];
  float* out = (float*)d_out;

  nuint4* packed = (nuint4*)d_ws;  // 65.5 MB
  (void)ws_size;

  hipLaunchKernelGGL(repack_grids, dim3((kG3 + 255) / 256), dim3(256), 0,
                     stream, density, off_c, emo_c, packed);

  const int threads = 256;
  const int blocks  = (kR * 64) / threads;  // 2048
  hipLaunchKernelGGL(dvgo_fwd, dim3(blocks), dim3(threads), 0, stream,
                     rays_o, rays_d, jitter, em, (const uint4*)packed,
                     (const uint2*)packed, out);
}